// Round 3
// baseline (168.414 us; speedup 1.0000x reference)
//
#include <hip/hip_runtime.h>

// Locally-connected 2D conv, fp32.
// x:(8,32,64,64)  weights:(64,64,32,32,3,3)  bias:(32)  out:(8,32,64,64)
// out[b,o,i,j] = bias[o] + sum_{c,d4,d5} x[b,c,i+d5-1,j+d4-1] * W[i,j,o,c,d4,d5]
// (weight kernel dims spatially transposed vs patch, per 'bchwij,ijocwh->boij')
//
// Pipelined persistent-WG version: each 256-thread WG owns 4 consecutive
// locations (same i, j0..j0+3). While computing loc l it prefetches loc
// l+1's weights (9 dwordx4/thread, in regs) and x patch (9 dwords/thread,
// into the other LDS buffer) — one compute phase of latency cover for the
// no-reuse weight stream. Outputs held in regs, one dwordx4 store/thread.

#define NB 8
#define NC 32
#define NO 32
#define NH 64
#define NW 64
#define KK 288   // NC*3*3
#define K4 72    // KK/4
#define LOCS 4

__device__ __forceinline__ float reduce8(const float a[8], int kc) {
  // Butterfly reduce-scatter over the 8 kc-lanes: lane kc ends with the
  // full K-sum for batch b == kc.
  float p8[8];
#pragma unroll
  for (int b = 0; b < 8; ++b) p8[b] = __shfl_xor(a[b], 4);
  float c4[4];
#pragma unroll
  for (int b = 0; b < 4; ++b)
    c4[b] = (kc & 4) ? (a[b + 4] + p8[b + 4]) : (a[b] + p8[b]);
  float p4[4];
#pragma unroll
  for (int b = 0; b < 4; ++b) p4[b] = __shfl_xor(c4[b], 2);
  float c2[2];
#pragma unroll
  for (int b = 0; b < 2; ++b)
    c2[b] = (kc & 2) ? (c4[b + 2] + p4[b + 2]) : (c4[b] + p4[b]);
  float p2[2];
#pragma unroll
  for (int b = 0; b < 2; ++b) p2[b] = __shfl_xor(c2[b], 1);
  return (kc & 1) ? (c2[1] + p2[1]) : (c2[0] + p2[0]);
}

__global__ __launch_bounds__(256, 4) void lc2d_kernel(
    const float* __restrict__ x, const float* __restrict__ w,
    const float* __restrict__ bias, float* __restrict__ out) {
  const int g = blockIdx.x;            // 0..1023
  const int loc0 = g * LOCS;
  const int i = loc0 >> 6;             // LOCS divides 64 -> same i for all 4
  const int j0 = loc0 & 63;
  const int t = threadIdx.x;
  const int kc = t & 7;
  const int o = t >> 3;

  __shared__ float xs[2][NB * KK];     // 2 x 9216 B

  // ---- x-patch staging helpers (transpose (c,kw,kh)->k folded in) ----
  // xs[.][b*288 + c*9 + a*3 + bb] = x[b,c,i+bb-1,j+a-1], zero-padded.
  auto stage_load = [&](int l, float v[9]) {
#pragma unroll
    for (int r = 0; r < 9; ++r) {
      int e = t + r * 256;
      int b = e / KK;
      int k = e - b * KK;
      int c = k / 9;
      int r9 = k - c * 9;
      int a = r9 / 3;                  // kw (W axis offset)
      int bb = r9 - a * 3;             // kh (H axis offset)
      int y = i + bb - 1;
      int xc = j0 + l + a - 1;
      v[r] = 0.f;
      if ((unsigned)y < 64u && (unsigned)xc < 64u)
        v[r] = x[((b * NC + c) * NH + y) * NW + xc];
    }
  };
  auto stage_write = [&](int bufi, const float v[9]) {
#pragma unroll
    for (int r = 0; r < 9; ++r) xs[bufi][t + r * 256] = v[r];
  };

  const float bia = bias[o];
  const float4* xs4base = reinterpret_cast<const float4*>(&xs[0][0]);

  // ---- prologue: stage loc 0, prefetch weights for loc 0 ----
  {
    float v0[9];
    stage_load(0, v0);
    stage_write(0, v0);
  }
  float4 wcur[9];
  {
    const float4* wb = reinterpret_cast<const float4*>(w) +
                       ((size_t)loc0 * NO + o) * K4 + kc;
#pragma unroll
    for (int s = 0; s < 9; ++s) wcur[s] = wb[s * 8];
  }
  __syncthreads();

  float tot[LOCS];

#pragma unroll
  for (int l = 0; l < LOCS; ++l) {
    // prefetch next location's x (regs) and weights (regs)
    float vnext[9];
    float4 wnext[9];
    if (l + 1 < LOCS) {
      stage_load(l + 1, vnext);
      const float4* wb = reinterpret_cast<const float4*>(w) +
                         ((size_t)(loc0 + l + 1) * NO + o) * K4 + kc;
#pragma unroll
      for (int s = 0; s < 9; ++s) wnext[s] = wb[s * 8];
    }

    // compute loc l from xs[l&1] + wcur
    const float4* xs4 = xs4base + (l & 1) * (NB * K4);
    float acc[NB];
#pragma unroll
    for (int b = 0; b < NB; ++b) acc[b] = 0.f;
#pragma unroll
    for (int s = 0; s < 9; ++s) {
      float4 wv = wcur[s];
#pragma unroll
      for (int b = 0; b < NB; ++b) {
        float4 xv = xs4[b * K4 + s * 8 + kc];   // bank 4*kc: conflict-free
        acc[b] = fmaf(wv.x, xv.x, acc[b]);
        acc[b] = fmaf(wv.y, xv.y, acc[b]);
        acc[b] = fmaf(wv.z, xv.z, acc[b]);
        acc[b] = fmaf(wv.w, xv.w, acc[b]);
      }
    }

    // write next x-patch into the other LDS buffer (overlaps with other
    // waves' compute on xs[l&1]; barrier below publishes it)
    if (l + 1 < LOCS) stage_write((l + 1) & 1, vnext);

    tot[l] = reduce8(acc, kc) + bia;

    if (l + 1 < LOCS) {
      __syncthreads();
#pragma unroll
      for (int s = 0; s < 9; ++s) wcur[s] = wnext[s];
    }
  }

  // one dwordx4 store per thread: out[kc, o, i, j0..j0+3]
  float4 o4;
  o4.x = tot[0]; o4.y = tot[1]; o4.z = tot[2]; o4.w = tot[3];
  *reinterpret_cast<float4*>(&out[((kc * NO + o) * NH + i) * NW + j0]) = o4;
}

extern "C" void kernel_launch(void* const* d_in, const int* in_sizes, int n_in,
                              void* d_out, int out_size, void* d_ws, size_t ws_size,
                              hipStream_t stream) {
  const float* x    = (const float*)d_in[0];
  const float* w    = (const float*)d_in[1];
  const float* bias = (const float*)d_in[2];
  float* out = (float*)d_out;
  lc2d_kernel<<<dim3(NH * NW / LOCS), dim3(256), 0, stream>>>(x, w, bias, out);
}

// Round 4
// 40.217 us; speedup vs baseline: 4.1876x; 4.1876x over previous
//
#include <hip/hip_runtime.h>

// Locally-connected 2D conv, fp32.
// x:(8,32,64,64)  weights:(64,64,32,32,3,3)  bias:(32)  out:(8,32,64,64)
// out[b,o,i,j] = bias[o] + sum_{c,d4,d5} x[b,c,i+d5-1,j+d4-1] * W[i,j,o,c,d4,d5]
//
// Persistent 512x256 grid, 8 locations (same row i) per WG.
// - x staged COALESCED into a natural-order LDS slab (rows of 10 contiguous
//   floats shared by all 8 locs) -- kills the uncoalesced per-loc patch loads
//   (64 lines/instr) that made R0-R2 address-transaction-bound.
// - per-loc (c,kw,kh)-ordered buffer built by an LDS->LDS transpose (TA-free),
//   double-buffered; compute reads are conflict-free broadcast ds_read_b128.
// - weights direct global->reg, rotating wreg[2][9] prefetch (next loc's
//   chunk s issued right after this loc's chunk s is consumed); raw s_barrier
//   + lgkmcnt(0) only, so weight prefetches stay in flight across barriers.
// - thread (bg,og,kc) computes o=2og,2og+1 for b=4bg..4bg+3 over K-chunk kc;
//   butterfly reduce-scatter over 8 kc-lanes; per-loc scalars parked in LDS
//   obuf; final 2x dwordx4 contiguous store per thread.

#define NB 8
#define NC 32
#define NO 32
#define NH 64
#define NW 64
#define KK 288   // NC*3*3
#define K4 72    // KK/4
#define LOCS 8
#define XCOLS 10                  // j0-1 .. j0+8
#define NROWS (NB * NC * 3)       // 768
#define XNAT_SZ (NROWS * XCOLS)   // 7680
#define XT_SZ (NB * KK)           // 2304

__device__ __forceinline__ float reduce8(const float a[8], int kc) {
  // Butterfly reduce-scatter over the 8 kc-lanes: lane kc ends with the
  // full K-sum of slot kc.
  float p8[8];
#pragma unroll
  for (int b = 0; b < 8; ++b) p8[b] = __shfl_xor(a[b], 4);
  float c4[4];
#pragma unroll
  for (int b = 0; b < 4; ++b)
    c4[b] = (kc & 4) ? (a[b + 4] + p8[b + 4]) : (a[b] + p8[b]);
  float p4[4];
#pragma unroll
  for (int b = 0; b < 4; ++b) p4[b] = __shfl_xor(c4[b], 2);
  float c2[2];
#pragma unroll
  for (int b = 0; b < 2; ++b)
    c2[b] = (kc & 2) ? (c4[b + 2] + p4[b + 2]) : (c4[b] + p4[b]);
  float p2[2];
#pragma unroll
  for (int b = 0; b < 2; ++b) p2[b] = __shfl_xor(c2[b], 1);
  return (kc & 1) ? (c2[1] + p2[1]) : (c2[0] + p2[0]);
}

__global__ __launch_bounds__(256) void lc2d_kernel(
    const float* __restrict__ x, const float* __restrict__ w,
    const float* __restrict__ bias, float* __restrict__ out) {
  const int g = blockIdx.x;            // 0..511
  const int loc0 = g * LOCS;
  const int i = loc0 >> 6;             // 8 divides 64 -> same i for all locs
  const int j0 = loc0 & 63;
  const int t = threadIdx.x;
  const int kc = t & 7;
  const int og = (t >> 3) & 15;
  const int bg = t >> 7;               // 0..1
  const int o0 = og * 2;
  const int b0 = bg * 4;
  const int o_out = o0 + (kc >> 2);    // this thread's final (o, b)
  const int b_out = b0 + (kc & 3);

  __shared__ float xnat[XNAT_SZ];      // 30720 B, natural order, all 8 locs
  __shared__ float xt[2][XT_SZ];       // 18432 B, per-loc (c,kw,kh) order
  __shared__ float obuf[LOCS][256];    // 8192 B, per-loc results

  const float bia = bias[o_out];

  // ---- coalesced stage: row=(b,c,yy), cols cc=0..9 -> xc=j0-1+cc ----
#pragma unroll
  for (int it = 0; it < 30; ++it) {
    int e = t + it * 256;
    int row = e / XCOLS;
    int cc = e - row * XCOLS;
    int bc = row / 3;                  // b*32 + c
    int yy = row - bc * 3;
    int y = i + yy - 1;
    int xc = j0 + cc - 1;
    float v = 0.f;
    if ((unsigned)y < 64u && (unsigned)xc < 64u)
      v = x[(bc * NH + y) * NW + xc];
    xnat[e] = v;
  }
  asm volatile("s_waitcnt lgkmcnt(0)\n\ts_barrier" ::: "memory");

  // ---- LDS->LDS transpose: xt[buf][b*288 + c*9 + a*3 + bb] ----
  auto transpose = [&](int l, int buf) {
#pragma unroll
    for (int r = 0; r < 9; ++r) {
      int e = t + r * 256;             // < 2304
      int b = e / KK;
      int k = e - b * KK;
      int c = k / 9;
      int r9 = k - c * 9;
      int a = r9 / 3;                  // kw
      int bb = r9 - a * 3;             // kh
      xt[buf][e] = xnat[((b * NC + c) * 3 + bb) * XCOLS + l + a];
    }
  };

  transpose(0, 0);

  // ---- weights: rotating register double-buffer ----
  float4 wreg[2][9];
  {
    const float4* p0 = reinterpret_cast<const float4*>(w) +
                       ((size_t)loc0 * NO + o0) * K4 + kc;
    const float4* p1 = p0 + K4;
#pragma unroll
    for (int s = 0; s < 9; ++s) { wreg[0][s] = p0[s * 8]; wreg[1][s] = p1[s * 8]; }
  }
  asm volatile("s_waitcnt lgkmcnt(0)\n\ts_barrier" ::: "memory");

#pragma unroll 1
  for (int l = 0; l < LOCS - 1; ++l) {
    const int cur = l & 1;
    transpose(l + 1, cur ^ 1);         // overlaps with compute below

    const float4* xt4 = reinterpret_cast<const float4*>(&xt[cur][0]);
    const float4* pn0 = reinterpret_cast<const float4*>(w) +
                        ((size_t)(loc0 + l + 1) * NO + o0) * K4 + kc;
    const float4* pn1 = pn0 + K4;

    float acc[2][4];
#pragma unroll
    for (int oi = 0; oi < 2; ++oi)
#pragma unroll
      for (int bi = 0; bi < 4; ++bi) acc[oi][bi] = 0.f;

#pragma unroll
    for (int s = 0; s < 9; ++s) {
      float4 w0 = wreg[0][s], w1 = wreg[1][s];
#pragma unroll
      for (int bi = 0; bi < 4; ++bi) {
        float4 xv = xt4[(b0 + bi) * K4 + s * 8 + kc];  // bank 4kc: clean
        acc[0][bi] = fmaf(w0.x, xv.x, acc[0][bi]);
        acc[0][bi] = fmaf(w0.y, xv.y, acc[0][bi]);
        acc[0][bi] = fmaf(w0.z, xv.z, acc[0][bi]);
        acc[0][bi] = fmaf(w0.w, xv.w, acc[0][bi]);
        acc[1][bi] = fmaf(w1.x, xv.x, acc[1][bi]);
        acc[1][bi] = fmaf(w1.y, xv.y, acc[1][bi]);
        acc[1][bi] = fmaf(w1.z, xv.z, acc[1][bi]);
        acc[1][bi] = fmaf(w1.w, xv.w, acc[1][bi]);
      }
      // rotate: next loc's chunk s into the just-freed registers
      wreg[0][s] = pn0[s * 8];
      wreg[1][s] = pn1[s * 8];
    }

    float a8[8];
#pragma unroll
    for (int oi = 0; oi < 2; ++oi)
#pragma unroll
      for (int bi = 0; bi < 4; ++bi) a8[oi * 4 + bi] = acc[oi][bi];
    obuf[l][t] = reduce8(a8, kc);
    asm volatile("s_waitcnt lgkmcnt(0)\n\ts_barrier" ::: "memory");
  }

  // ---- epilogue: last loc, no prefetch, no trailing barrier ----
  {
    const float4* xt4 =
        reinterpret_cast<const float4*>(&xt[(LOCS - 1) & 1][0]);
    float acc[2][4];
#pragma unroll
    for (int oi = 0; oi < 2; ++oi)
#pragma unroll
      for (int bi = 0; bi < 4; ++bi) acc[oi][bi] = 0.f;
#pragma unroll
    for (int s = 0; s < 9; ++s) {
      float4 w0 = wreg[0][s], w1 = wreg[1][s];
#pragma unroll
      for (int bi = 0; bi < 4; ++bi) {
        float4 xv = xt4[(b0 + bi) * K4 + s * 8 + kc];
        acc[0][bi] = fmaf(w0.x, xv.x, acc[0][bi]);
        acc[0][bi] = fmaf(w0.y, xv.y, acc[0][bi]);
        acc[0][bi] = fmaf(w0.z, xv.z, acc[0][bi]);
        acc[0][bi] = fmaf(w0.w, xv.w, acc[0][bi]);
        acc[1][bi] = fmaf(w1.x, xv.x, acc[1][bi]);
        acc[1][bi] = fmaf(w1.y, xv.y, acc[1][bi]);
        acc[1][bi] = fmaf(w1.z, xv.z, acc[1][bi]);
        acc[1][bi] = fmaf(w1.w, xv.w, acc[1][bi]);
      }
    }
    float a8[8];
#pragma unroll
    for (int oi = 0; oi < 2; ++oi)
#pragma unroll
      for (int bi = 0; bi < 4; ++bi) a8[oi * 4 + bi] = acc[oi][bi];
    obuf[LOCS - 1][t] = reduce8(a8, kc);
  }

  // ---- final contiguous store: out[b_out, o_out, i, j0..j0+7] ----
  // obuf[l][t] entries were written by this thread itself (slot kc mapping
  // is identical for every loc) -> no barrier needed.
  float4 fa, fb;
  fa.x = obuf[0][t] + bia; fa.y = obuf[1][t] + bia;
  fa.z = obuf[2][t] + bia; fa.w = obuf[3][t] + bia;
  fb.x = obuf[4][t] + bia; fb.y = obuf[5][t] + bia;
  fb.z = obuf[6][t] + bia; fb.w = obuf[7][t] + bia;
  float* op = &out[((b_out * NO + o_out) * NH + i) * NW + j0];
  *reinterpret_cast<float4*>(op) = fa;
  *reinterpret_cast<float4*>(op + 4) = fb;
}

extern "C" void kernel_launch(void* const* d_in, const int* in_sizes, int n_in,
                              void* d_out, int out_size, void* d_ws, size_t ws_size,
                              hipStream_t stream) {
  const float* x    = (const float*)d_in[0];
  const float* w    = (const float*)d_in[1];
  const float* bias = (const float*)d_in[2];
  float* out = (float*)d_out;
  lc2d_kernel<<<dim3(NH * NW / LOCS), dim3(256), 0, stream>>>(x, w, bias, out);
}

// Round 5
// 34.126 us; speedup vs baseline: 4.9350x; 1.1785x over previous
//
#include <hip/hip_runtime.h>

// Locally-connected 2D conv, fp32.
// x:(8,32,64,64)  weights:(64,64,32,32,3,3)  bias:(32)  out:(8,32,64,64)
// out[b,o,i,j] = bias[o] + sum_{c,d4,d5} x[b,c,i+d5-1,j+d4-1] * W[i,j,o,c,d4,d5]
//
// R4: 1024 WGs x 256thr, 4 locations (same row i) per WG, 4 WGs/CU.
// - XCD-bijective swizzle: g=(bid&7)*128+(bid>>3) puts each 8-i-row band
//   (and ALL j-blocks of every output row) on one XCD -> out-line write
//   merging in that XCD's L2, and x working set/XCD ~1.3MB (L2-resident).
// - x staged coalesced into natural-order slab xnat (rows of 6 floats),
//   per-loc (c,kw,kh)-ordered xt built by LDS->LDS transpose (single buf;
//   4 WGs/CU of TLP hide the 2 barriers/loc).
// - weights global->reg with rotating wreg[2][9] prefetch (next loc's chunk
//   s loaded right after this loc's chunk s is consumed); barriers are raw
//   s_barrier (+lgkmcnt only where LDS data must publish) so weight loads
//   stay in flight across them.
// - thread (bg,og,kc): o=2og..2og+1, b=4bg..4bg+3, K-chunk kc; butterfly
//   reduce-scatter over kc-lanes; obuf -> one float4 store per thread.

#define NB 8
#define NC 32
#define NO 32
#define NH 64
#define NW 64
#define KK 288   // NC*3*3
#define K4 72    // KK/4
#define LOCS 4
#define XCOLS 6                   // j0-1 .. j0+4
#define NROWS (NB * NC * 3)       // 768
#define XNAT_SZ (NROWS * XCOLS)   // 4608
#define XT_SZ (NB * KK)           // 2304

__device__ __forceinline__ float reduce8(const float a[8], int kc) {
  // Butterfly reduce-scatter over the 8 kc-lanes: lane kc ends with the
  // full K-sum of slot kc.
  float p8[8];
#pragma unroll
  for (int b = 0; b < 8; ++b) p8[b] = __shfl_xor(a[b], 4);
  float c4[4];
#pragma unroll
  for (int b = 0; b < 4; ++b)
    c4[b] = (kc & 4) ? (a[b + 4] + p8[b + 4]) : (a[b] + p8[b]);
  float p4[4];
#pragma unroll
  for (int b = 0; b < 4; ++b) p4[b] = __shfl_xor(c4[b], 2);
  float c2[2];
#pragma unroll
  for (int b = 0; b < 2; ++b)
    c2[b] = (kc & 2) ? (c4[b + 2] + p4[b + 2]) : (c4[b] + p4[b]);
  float p2[2];
#pragma unroll
  for (int b = 0; b < 2; ++b) p2[b] = __shfl_xor(c2[b], 1);
  return (kc & 1) ? (c2[1] + p2[1]) : (c2[0] + p2[0]);
}

__global__ __launch_bounds__(256, 4) void lc2d_kernel(
    const float* __restrict__ x, const float* __restrict__ w,
    const float* __restrict__ bias, float* __restrict__ out) {
  const int bid = blockIdx.x;          // 0..1023
  const int g = (bid & 7) * 128 + (bid >> 3);   // XCD-cluster (bijective)
  const int loc0 = g * LOCS;
  const int i = loc0 >> 6;             // 4 divides 64 -> same i for all locs
  const int j0 = loc0 & 63;
  const int t = threadIdx.x;
  const int kc = t & 7;
  const int og = (t >> 3) & 15;
  const int bg = t >> 7;               // 0..1
  const int o0 = og * 2;
  const int b0 = bg * 4;
  const int o_out = o0 + (kc >> 2);
  const int b_out = b0 + (kc & 3);

  __shared__ __align__(16) float xnat[XNAT_SZ];  // 18432 B
  __shared__ __align__(16) float xt[XT_SZ];      //  9216 B
  __shared__ __align__(16) float obuf[LOCS][256];//  4096 B

  const float bia = bias[o_out];

  // ---- issue loc0 weight loads first (independent of LDS) ----
  float4 wreg[2][9];
  const float4* wb0 = reinterpret_cast<const float4*>(w) +
                      ((size_t)loc0 * NO + o0) * K4 + kc;
  const float4* wb1 = wb0 + K4;
#pragma unroll
  for (int s = 0; s < 9; ++s) { wreg[0][s] = wb0[s * 8]; wreg[1][s] = wb1[s * 8]; }

  // ---- coalesced x stage: row=(b,c,yy), cols cc=0..5 -> xc=j0-1+cc ----
#pragma unroll
  for (int it = 0; it < 18; ++it) {
    int e = t + it * 256;
    int row = e / XCOLS;
    int cc = e - row * XCOLS;
    int bc = row / 3;                  // b*32 + c
    int yy = row - bc * 3;
    int y = i + yy - 1;
    int xc = j0 + cc - 1;
    float v = 0.f;
    if ((unsigned)y < 64u && (unsigned)xc < 64u)
      v = x[(bc * NH + y) * NW + xc];
    xnat[e] = v;
  }
  asm volatile("s_waitcnt lgkmcnt(0)\n\ts_barrier" ::: "memory");

  // ---- transpose-read helper: loc l, element e=t+r*256 ----
  // xt[e] with e = b*288 + c*9 + a*3 + bb  <-  xnat[(bc*3+bb)*6 + l + a]
  auto tr_read = [&](int l, float v[9]) {
#pragma unroll
    for (int r = 0; r < 9; ++r) {
      int e = t + r * 256;
      int b = e / KK;
      int k = e - b * KK;
      int c = k / 9;
      int r9 = k - c * 9;
      int a = r9 / 3;
      int bb = r9 - a * 3;
      v[r] = xnat[((b * NC + c) * 3 + bb) * XCOLS + l + a];
    }
  };

  // prologue: build xt for loc 0
  {
    float v0[9];
    tr_read(0, v0);
#pragma unroll
    for (int r = 0; r < 9; ++r) xt[t + r * 256] = v0[r];
  }
  asm volatile("s_waitcnt lgkmcnt(0)\n\ts_barrier" ::: "memory");

  const float4* xt4 = reinterpret_cast<const float4*>(xt);

#pragma unroll 1
  for (int l = 0; l < LOCS - 1; ++l) {
    // transpose-read next loc into regs (xnat is never overwritten)
    float vnext[9];
    tr_read(l + 1, vnext);

    const float4* pn0 = reinterpret_cast<const float4*>(w) +
                        ((size_t)(loc0 + l + 1) * NO + o0) * K4 + kc;
    const float4* pn1 = pn0 + K4;

    float acc[2][4];
#pragma unroll
    for (int oi = 0; oi < 2; ++oi)
#pragma unroll
      for (int bi = 0; bi < 4; ++bi) acc[oi][bi] = 0.f;

#pragma unroll
    for (int s = 0; s < 9; ++s) {
      float4 w0 = wreg[0][s], w1 = wreg[1][s];
#pragma unroll
      for (int bi = 0; bi < 4; ++bi) {
        float4 xv = xt4[(b0 + bi) * K4 + s * 8 + kc];  // bank 4kc: clean
        acc[0][bi] = fmaf(w0.x, xv.x, acc[0][bi]);
        acc[0][bi] = fmaf(w0.y, xv.y, acc[0][bi]);
        acc[0][bi] = fmaf(w0.z, xv.z, acc[0][bi]);
        acc[0][bi] = fmaf(w0.w, xv.w, acc[0][bi]);
        acc[1][bi] = fmaf(w1.x, xv.x, acc[1][bi]);
        acc[1][bi] = fmaf(w1.y, xv.y, acc[1][bi]);
        acc[1][bi] = fmaf(w1.z, xv.z, acc[1][bi]);
        acc[1][bi] = fmaf(w1.w, xv.w, acc[1][bi]);
      }
      // rotate: next loc's chunk s into the just-freed registers
      wreg[0][s] = pn0[s * 8];
      wreg[1][s] = pn1[s * 8];
    }

    float a8[8];
#pragma unroll
    for (int oi = 0; oi < 2; ++oi)
#pragma unroll
      for (int bi = 0; bi < 4; ++bi) a8[oi * 4 + bi] = acc[oi][bi];
    obuf[l][t] = reduce8(a8, kc);

    // publish next xt: all waves' reads of current xt are complete (data-dep)
    asm volatile("s_barrier" ::: "memory");
#pragma unroll
    for (int r = 0; r < 9; ++r) xt[t + r * 256] = vnext[r];
    asm volatile("s_waitcnt lgkmcnt(0)\n\ts_barrier" ::: "memory");
  }

  // ---- epilogue: last loc, no prefetch ----
  {
    float acc[2][4];
#pragma unroll
    for (int oi = 0; oi < 2; ++oi)
#pragma unroll
      for (int bi = 0; bi < 4; ++bi) acc[oi][bi] = 0.f;
#pragma unroll
    for (int s = 0; s < 9; ++s) {
      float4 w0 = wreg[0][s], w1 = wreg[1][s];
#pragma unroll
      for (int bi = 0; bi < 4; ++bi) {
        float4 xv = xt4[(b0 + bi) * K4 + s * 8 + kc];
        acc[0][bi] = fmaf(w0.x, xv.x, acc[0][bi]);
        acc[0][bi] = fmaf(w0.y, xv.y, acc[0][bi]);
        acc[0][bi] = fmaf(w0.z, xv.z, acc[0][bi]);
        acc[0][bi] = fmaf(w0.w, xv.w, acc[0][bi]);
        acc[1][bi] = fmaf(w1.x, xv.x, acc[1][bi]);
        acc[1][bi] = fmaf(w1.y, xv.y, acc[1][bi]);
        acc[1][bi] = fmaf(w1.z, xv.z, acc[1][bi]);
        acc[1][bi] = fmaf(w1.w, xv.w, acc[1][bi]);
      }
    }
    float a8[8];
#pragma unroll
    for (int oi = 0; oi < 2; ++oi)
#pragma unroll
      for (int bi = 0; bi < 4; ++bi) a8[oi * 4 + bi] = acc[oi][bi];
    obuf[LOCS - 1][t] = reduce8(a8, kc);
  }

  // ---- final store: out[b_out, o_out, i, j0..j0+3] (own obuf entries) ----
  float4 fa;
  fa.x = obuf[0][t] + bia;
  fa.y = obuf[1][t] + bia;
  fa.z = obuf[2][t] + bia;
  fa.w = obuf[3][t] + bia;
  *reinterpret_cast<float4*>(&out[((b_out * NO + o_out) * NH + i) * NW + j0]) = fa;
}

extern "C" void kernel_launch(void* const* d_in, const int* in_sizes, int n_in,
                              void* d_out, int out_size, void* d_ws, size_t ws_size,
                              hipStream_t stream) {
  const float* x    = (const float*)d_in[0];
  const float* w    = (const float*)d_in[1];
  const float* bias = (const float*)d_in[2];
  float* out = (float*)d_out;
  lc2d_kernel<<<dim3(NH * NW / LOCS), dim3(256), 0, stream>>>(x, w, bias, out);
}